// Round 10
// baseline (850.543 us; speedup 1.0000x reference)
//
#include <hip/hip_runtime.h>
#include <hip/hip_bf16.h>
#include <math.h>

#define S_LEN 2048
#define DIM   1024
#define NH    16
#define NKVH  4
#define HD    64
#define KVDIM 256
#define NEG_BIG (-1e30f)

typedef __hip_bfloat16 bf16;

// ---------------------------------------------------------------------------
// GEMM: C[M,N] = A[M,K] * B[N,K]^T (verified)
// ---------------------------------------------------------------------------
__global__ __launch_bounds__(256) void gemm_nt(
    const float* __restrict__ A, const float* __restrict__ B,
    float* __restrict__ C, int M, int N, int K) {
    __shared__ float As[64][36];
    __shared__ float Bs[64][36];
    const int tid = threadIdx.x;
    const int bm = blockIdx.y * 64;
    const int bn = blockIdx.x * 64;
    const int lr = tid >> 2;
    const int lc = (tid & 3) << 3;
    const int ty = tid >> 4;
    const int tx = tid & 15;
    float acc[4][4] = {};
    const float* ap = A + (size_t)(bm + lr) * K + lc;
    const float* bp = B + (size_t)(bn + lr) * K + lc;
    for (int k0 = 0; k0 < K; k0 += 32) {
        float4 a0 = *(const float4*)(ap + k0);
        float4 a1 = *(const float4*)(ap + k0 + 4);
        float4 b0 = *(const float4*)(bp + k0);
        float4 b1 = *(const float4*)(bp + k0 + 4);
        *(float4*)&As[lr][lc]     = a0;
        *(float4*)&As[lr][lc + 4] = a1;
        *(float4*)&Bs[lr][lc]     = b0;
        *(float4*)&Bs[lr][lc + 4] = b1;
        __syncthreads();
        #pragma unroll
        for (int kk = 0; kk < 32; kk += 4) {
            float4 a[4], b[4];
            #pragma unroll
            for (int i = 0; i < 4; ++i) a[i] = *(const float4*)&As[ty + 16*i][kk];
            #pragma unroll
            for (int j = 0; j < 4; ++j) b[j] = *(const float4*)&Bs[tx + 16*j][kk];
            #pragma unroll
            for (int i = 0; i < 4; ++i)
                #pragma unroll
                for (int j = 0; j < 4; ++j)
                    acc[i][j] += a[i].x*b[j].x + a[i].y*b[j].y +
                                 a[i].z*b[j].z + a[i].w*b[j].w;
        }
        __syncthreads();
    }
    #pragma unroll
    for (int i = 0; i < 4; ++i) {
        const int row = bm + ty + 16*i;
        #pragma unroll
        for (int j = 0; j < 4; ++j)
            C[(size_t)row * N + bn + tx + 16*j] = acc[i][j];
    }
}

__global__ __launch_bounds__(256) void gemm_kvg(
    const float* __restrict__ A, const float* __restrict__ B0,
    const float* __restrict__ B1, const float* __restrict__ B2,
    float* __restrict__ C) {
    __shared__ float As[64][36];
    __shared__ float Bs[64][36];
    const int tid = threadIdx.x;
    const int w  = blockIdx.x >> 2;
    const int bn = (blockIdx.x & 3) * 64;
    const int bm = blockIdx.y * 64;
    const float* B = (w == 0) ? B0 : (w == 1) ? B1 : B2;
    float* Cw = C + (size_t)w * S_LEN * KVDIM;
    const int K = DIM, N = KVDIM;
    const int lr = tid >> 2;
    const int lc = (tid & 3) << 3;
    const int ty = tid >> 4;
    const int tx = tid & 15;
    float acc[4][4] = {};
    const float* ap = A + (size_t)(bm + lr) * K + lc;
    const float* bp = B + (size_t)(bn + lr) * K + lc;
    for (int k0 = 0; k0 < K; k0 += 32) {
        float4 a0 = *(const float4*)(ap + k0);
        float4 a1 = *(const float4*)(ap + k0 + 4);
        float4 b0 = *(const float4*)(bp + k0);
        float4 b1 = *(const float4*)(bp + k0 + 4);
        *(float4*)&As[lr][lc]     = a0;
        *(float4*)&As[lr][lc + 4] = a1;
        *(float4*)&Bs[lr][lc]     = b0;
        *(float4*)&Bs[lr][lc + 4] = b1;
        __syncthreads();
        #pragma unroll
        for (int kk = 0; kk < 32; kk += 4) {
            float4 a[4], b[4];
            #pragma unroll
            for (int i = 0; i < 4; ++i) a[i] = *(const float4*)&As[ty + 16*i][kk];
            #pragma unroll
            for (int j = 0; j < 4; ++j) b[j] = *(const float4*)&Bs[tx + 16*j][kk];
            #pragma unroll
            for (int i = 0; i < 4; ++i)
                #pragma unroll
                for (int j = 0; j < 4; ++j)
                    acc[i][j] += a[i].x*b[j].x + a[i].y*b[j].y +
                                 a[i].z*b[j].z + a[i].w*b[j].w;
        }
        __syncthreads();
    }
    #pragma unroll
    for (int i = 0; i < 4; ++i) {
        const int row = bm + ty + 16*i;
        #pragma unroll
        for (int j = 0; j < 4; ++j)
            Cw[(size_t)row * N + bn + tx + 16*j] = acc[i][j];
    }
}

// ---------------------------------------------------------------------------
// Postproc (verified)
// ---------------------------------------------------------------------------
__device__ __forceinline__ void rms_rotary(float* p, int s, int lane, float gain) {
    float x = p[lane];
    float ss = x * x;
    #pragma unroll
    for (int o = 32; o > 0; o >>= 1) ss += __shfl_xor(ss, o);
    float n = x * rsqrtf(ss * (1.0f/64.0f) + 1.1920928955078125e-7f);
    float other = __shfl_xor(n, 32);
    int i = lane & 31;
    float af  = (float)(((double)(2*i) / 64.0) * 3.14159265358979323846);
    float ang = (float)s * af;
    float radius = 1.0f / (1.0f + 0.01f * (float)s);
    float c  = radius * (float)cos((double)ang);
    float sn = radius * (float)sin((double)ang);
    float out = n * c + ((lane < 32) ? other * sn : -other * sn);
    p[lane] = out * gain;
}

__global__ __launch_bounds__(64) void postproc(
    float* __restrict__ Qp, float* __restrict__ Kp, float* __restrict__ Vp,
    const float* __restrict__ Gp, const float* __restrict__ qgain) {
    const int s = blockIdx.x;
    const int unit = blockIdx.y;
    const int lane = threadIdx.x;
    if (unit < NH) {
        rms_rotary(Qp + (size_t)s * DIM + unit * HD, s, lane, qgain[unit]);
    } else if (unit < NH + NKVH) {
        rms_rotary(Kp + (size_t)s * KVDIM + (unit - NH) * HD, s, lane, 1.0f);
    } else {
        const int h = unit - NH - NKVH;
        float* v = Vp + (size_t)s * KVDIM + h * HD;
        const float* g = Gp + (size_t)s * KVDIM + h * HD;
        float gv = g[lane];
        v[lane] = v[lane] / (1.0f + __expf(-gv));
    }
}

// ---------------------------------------------------------------------------
// Flash attention v2.1: identical to round 9 EXCEPT __launch_bounds__(256,2).
// Round 9's missing launch_bounds made HIP assume 1024-thread blocks, capping
// VGPRs at 64 -> q[32]/acc[32]/s[32] spilled to scratch -> 669 MB of HBM
// traffic per dispatch (measured). 256-thread bound gives the ~130 VGPRs this
// kernel needs with zero spill.
// ---------------------------------------------------------------------------
__global__ __launch_bounds__(256, 2) void attn_kernel(
    const float* __restrict__ Qp, const float* __restrict__ Kp,
    const float* __restrict__ Vp, float* __restrict__ Aout) {
    __shared__ float lds[9216];           // 4 waves * (K 32x36 + V 32x36)
    __shared__ float mbuf[3][64], lbuf[3][64];
    const int qt   = 31 - blockIdx.x;     // heavy q-tiles dispatch first
    const int h    = blockIdx.y;
    const int half = blockIdx.z;
    const int kvh  = h >> 2;
    const int tid  = threadIdx.x;
    const int w    = tid >> 6;            // wave 0..3
    const int lane = tid & 63;
    const int r    = qt * 64 + lane;      // this lane's q row
    float* KsW = &lds[w * 2304];
    float* VsW = KsW + 1152;

    float q[32], acc[32] = {};
    {
        const float* qp = Qp + (size_t)r * DIM + h * HD + half * 32;
        #pragma unroll
        for (int d = 0; d < 32; d += 4) *(float4*)&q[d] = *(const float4*)(qp + d);
    }
    float m = NEG_BIG, l = 0.f;
    const float scale = 0.17677669529663687f;  // 1/sqrt(32)
    const int srow = lane >> 1;
    const int scol = (lane & 1) * 16;
    const int nkt = 2 * qt + 2;           // key tiles covering rows <= qt*64+63

    for (int kb = w; kb < nkt; kb += 4) {
        // stage this wave's K/V tile (wave-synchronous, no barrier needed)
        {
            const size_t base = (size_t)(kb * 32 + srow) * KVDIM + kvh * HD + half * 32 + scol;
            const float* kp = Kp + base;
            const float* vp = Vp + base;
            float* kd = &KsW[srow * 36 + scol];
            float* vd = &VsW[srow * 36 + scol];
            #pragma unroll
            for (int c = 0; c < 16; c += 4) {
                *(float4*)(kd + c) = *(const float4*)(kp + c);
                *(float4*)(vd + c) = *(const float4*)(vp + c);
            }
        }
        // phase 1: 32 scores into registers, causal mask, tile max
        float s[32];
        const int j0 = kb * 32;
        #pragma unroll
        for (int j = 0; j < 32; ++j) {
            const float* kr = &KsW[j * 36];
            float a = 0.f;
            #pragma unroll
            for (int d = 0; d < 32; d += 4) {
                float4 kv = *(const float4*)(kr + d);
                a += q[d]*kv.x + q[d+1]*kv.y + q[d+2]*kv.z + q[d+3]*kv.w;
            }
            s[j] = (j0 + j > r) ? NEG_BIG : a * scale;
        }
        float tm = s[0];
        #pragma unroll
        for (int j = 1; j < 32; ++j) tm = fmaxf(tm, s[j]);
        // phase 2: single rescale per tile, then 1-FMA/dim PV accumulate
        const float mn = fmaxf(m, tm);
        const float al = __expf(m - mn);
        m = mn; l *= al;
        #pragma unroll
        for (int d = 0; d < 32; ++d) acc[d] *= al;
        #pragma unroll
        for (int j = 0; j < 32; ++j) {
            const float p = __expf(s[j] - mn);
            l += p;
            const float* vr = &VsW[j * 36];
            #pragma unroll
            for (int d = 0; d < 32; d += 4) {
                float4 vv = *(const float4*)(vr + d);
                acc[d]   += p * vv.x;
                acc[d+1] += p * vv.y;
                acc[d+2] += p * vv.z;
                acc[d+3] += p * vv.w;
            }
        }
    }

    // merge the 4 waves' partial flash states (stride 33 -> conflict-free)
    __syncthreads();
    if (w > 0) {
        float* dst = &lds[(w - 1) * 64 * 33 + lane * 33];
        #pragma unroll
        for (int d = 0; d < 32; ++d) dst[d] = acc[d];
        mbuf[w - 1][lane] = m;
        lbuf[w - 1][lane] = l;
    }
    __syncthreads();
    if (w == 0) {
        #pragma unroll
        for (int p = 0; p < 3; ++p) {
            const float mm = mbuf[p][lane];
            const float ll = lbuf[p][lane];
            const float mn = fmaxf(m, mm);
            const float a0 = __expf(m - mn);
            const float a1 = __expf(mm - mn);
            m = mn;
            l = l * a0 + ll * a1;
            const float* src = &lds[p * 64 * 33 + lane * 33];
            #pragma unroll
            for (int d = 0; d < 32; ++d) acc[d] = acc[d] * a0 + src[d] * a1;
        }
        const float inv = 1.f / l;
        float* o = Aout + (size_t)r * DIM + h * HD + half * 32;
        #pragma unroll
        for (int d = 0; d < 32; ++d) o[d] = acc[d] * inv;
    }
}

// ---------------------------------------------------------------------------
// Combine (verified)
// ---------------------------------------------------------------------------
__global__ __launch_bounds__(256) void combine_kernel(
    const float* __restrict__ A, const float* __restrict__ lambda_p,
    float* __restrict__ Y) {
    const int idx = blockIdx.x * 256 + threadIdx.x;
    const int c = idx & (DIM - 1);
    const int s = idx >> 10;
    const int hh = c >> 6;
    const int d = c & 63;
    const float* base = A + (size_t)s * DIM + hh * HD;
    const float lam = lambda_p[hh];
    float y;
    if (d < 32) y = base[d]      - lam * base[d + 32];
    else        y = base[d - 32] + lam * base[d];
    Y[idx] = y;
}

// ---------------------------------------------------------------------------
extern "C" void kernel_launch(void* const* d_in, const int* in_sizes, int n_in,
                              void* d_out, int out_size, void* d_ws, size_t ws_size,
                              hipStream_t stream) {
    const float* x  = (const float*)d_in[0];
    const float* Wq = (const float*)d_in[1];
    const float* Wk = (const float*)d_in[2];
    const float* Wv = (const float*)d_in[3];
    const float* Wg = (const float*)d_in[4];
    const float* Wo = (const float*)d_in[5];
    const float* qg = (const float*)d_in[6];
    const float* lp = (const float*)d_in[7];
    float* out = (float*)d_out;

    char* ws = (char*)d_ws;
    float* Qp  = (float*)(ws);
    float* KVG = (float*)(ws + (8u  << 20));
    float* Kp  = KVG;
    float* Vp  = KVG + (size_t)S_LEN * KVDIM;
    float* Gp  = KVG + (size_t)2 * S_LEN * KVDIM;
    float* Ao  = (float*)(ws + (14u << 20));
    float* Y   = (float*)ws;      // overlays dead Qp

    gemm_nt<<<dim3(DIM/64, S_LEN/64), 256, 0, stream>>>(x, Wq, Qp, S_LEN, DIM, DIM);
    gemm_kvg<<<dim3(12, S_LEN/64), 256, 0, stream>>>(x, Wk, Wv, Wg, KVG);
    postproc<<<dim3(S_LEN, NH + 2*NKVH), 64, 0, stream>>>(Qp, Kp, Vp, Gp, qg);
    attn_kernel<<<dim3(32, NH, 2), 256, 0, stream>>>(Qp, Kp, Vp, Ao);
    combine_kernel<<<dim3(S_LEN * DIM / 256), 256, 0, stream>>>(Ao, lp, Y);
    gemm_nt<<<dim3(DIM/64, S_LEN/64), 256, 0, stream>>>(Y, Wo, out, S_LEN, DIM, DIM);
}

// Round 11
// 378.560 us; speedup vs baseline: 2.2468x; 2.2468x over previous
//
#include <hip/hip_runtime.h>
#include <hip/hip_bf16.h>
#include <math.h>

#define S_LEN 2048
#define DIM   1024
#define NH    16
#define NKVH  4
#define HD    64
#define KVDIM 256

typedef __hip_bfloat16 bf16;
typedef __attribute__((ext_vector_type(8))) short short8;   // 8 bf16 (4 VGPRs)
typedef __attribute__((ext_vector_type(4))) float f32x4;

// ---------------------------------------------------------------------------
// fp32 -> bf16 cast (n multiple of 4)
// ---------------------------------------------------------------------------
__global__ __launch_bounds__(256) void cast_kernel(
    const float* __restrict__ s, bf16* __restrict__ d, int n) {
    const int i = (blockIdx.x * 256 + threadIdx.x) * 4;
    if (i < n) {
        float4 v = *(const float4*)(s + i);
        d[i]     = __float2bfloat16(v.x);
        d[i + 1] = __float2bfloat16(v.y);
        d[i + 2] = __float2bfloat16(v.z);
        d[i + 3] = __float2bfloat16(v.w);
    }
}

// ---------------------------------------------------------------------------
// bf16 MFMA GEMM: C[M,N] = A[M,K] * B[N,K]^T, fp32 out.
// 64x64 tile, BK=64, 256 threads = 4 waves (wave w: 16-row strip).
// Frag layouts (HW-verified per guide): A/B lane holds 8 consecutive K elems
// at k = quad*8 (+32 for 2nd mfma); C/D row = quad*4+reg, col = lane&15.
// LDS stride 72 shorts (pad 8) -> 2-way max bank aliasing (free).
// ---------------------------------------------------------------------------
__device__ __forceinline__ void gemm_core(
    const bf16* __restrict__ A, const bf16* __restrict__ B,
    float* __restrict__ C, int bm, int bn, int N, int K) {
    __shared__ short As[64 * 72];
    __shared__ short Bs[64 * 72];
    const int tid  = threadIdx.x;
    const int w    = tid >> 6;
    const int lane = tid & 63;
    const int quad = lane >> 4;
    const int lm   = lane & 15;
    const int row  = tid >> 2;
    const int kc   = (tid & 3) * 16;
    const bf16* ap = A + (size_t)(bm + row) * K + kc;
    const bf16* bp = B + (size_t)(bn + row) * K + kc;
    f32x4 acc[4] = {};
    const int aoff = (w * 16 + lm) * 72 + quad * 8;
    const int boff = lm * 72 + quad * 8;
    for (int k0 = 0; k0 < K; k0 += 64) {
        uint4 av0 = *(const uint4*)(ap + k0);
        uint4 av1 = *(const uint4*)(ap + k0 + 8);
        uint4 bv0 = *(const uint4*)(bp + k0);
        uint4 bv1 = *(const uint4*)(bp + k0 + 8);
        *(uint4*)&As[row * 72 + kc]     = av0;
        *(uint4*)&As[row * 72 + kc + 8] = av1;
        *(uint4*)&Bs[row * 72 + kc]     = bv0;
        *(uint4*)&Bs[row * 72 + kc + 8] = bv1;
        __syncthreads();
        short8 a0 = *(const short8*)&As[aoff];
        short8 a1 = *(const short8*)&As[aoff + 32];
        #pragma unroll
        for (int t = 0; t < 4; ++t) {
            short8 b0 = *(const short8*)&Bs[boff + t * 16 * 72];
            short8 b1 = *(const short8*)&Bs[boff + t * 16 * 72 + 32];
            acc[t] = __builtin_amdgcn_mfma_f32_16x16x32_bf16(a0, b0, acc[t], 0, 0, 0);
            acc[t] = __builtin_amdgcn_mfma_f32_16x16x32_bf16(a1, b1, acc[t], 0, 0, 0);
        }
        __syncthreads();
    }
    const int r0 = bm + w * 16 + quad * 4;
    #pragma unroll
    for (int t = 0; t < 4; ++t) {
        const int col = bn + t * 16 + lm;
        #pragma unroll
        for (int i = 0; i < 4; ++i)
            C[(size_t)(r0 + i) * N + col] = acc[t][i];
    }
}

__global__ __launch_bounds__(256) void gemm_bf16(
    const bf16* __restrict__ A, const bf16* __restrict__ B,
    float* __restrict__ C, int N, int K) {
    gemm_core(A, B, C, blockIdx.y * 64, blockIdx.x * 64, N, K);
}

// K/V/G fused: grid.x = 12, wsel = bx>>2 picks weight, output contiguous.
__global__ __launch_bounds__(256) void gemm_kvg_bf16(
    const bf16* __restrict__ A, const bf16* __restrict__ Bk,
    const bf16* __restrict__ Bv, const bf16* __restrict__ Bg,
    float* __restrict__ KVG) {
    const int wsel = blockIdx.x >> 2;
    const bf16* B = (wsel == 0) ? Bk : (wsel == 1) ? Bv : Bg;
    float* C = KVG + (size_t)wsel * S_LEN * KVDIM;
    gemm_core(A, B, C, blockIdx.y * 64, (blockIdx.x & 3) * 64, KVDIM, DIM);
}

// ---------------------------------------------------------------------------
// Postproc (verified, unchanged)
// ---------------------------------------------------------------------------
__device__ __forceinline__ void rms_rotary(float* p, int s, int lane, float gain) {
    float x = p[lane];
    float ss = x * x;
    #pragma unroll
    for (int o = 32; o > 0; o >>= 1) ss += __shfl_xor(ss, o);
    float n = x * rsqrtf(ss * (1.0f/64.0f) + 1.1920928955078125e-7f);
    float other = __shfl_xor(n, 32);
    int i = lane & 31;
    float af  = (float)(((double)(2*i) / 64.0) * 3.14159265358979323846);
    float ang = (float)s * af;
    float radius = 1.0f / (1.0f + 0.01f * (float)s);
    float c  = radius * (float)cos((double)ang);
    float sn = radius * (float)sin((double)ang);
    float out = n * c + ((lane < 32) ? other * sn : -other * sn);
    p[lane] = out * gain;
}

__global__ __launch_bounds__(64) void postproc(
    float* __restrict__ Qp, float* __restrict__ Kp, float* __restrict__ Vp,
    const float* __restrict__ Gp, const float* __restrict__ qgain) {
    const int s = blockIdx.x;
    const int unit = blockIdx.y;
    const int lane = threadIdx.x;
    if (unit < NH) {
        rms_rotary(Qp + (size_t)s * DIM + unit * HD, s, lane, qgain[unit]);
    } else if (unit < NH + NKVH) {
        rms_rotary(Kp + (size_t)s * KVDIM + (unit - NH) * HD, s, lane, 1.0f);
    } else {
        const int h = unit - NH - NKVH;
        float* v = Vp + (size_t)s * KVDIM + h * HD;
        const float* g = Gp + (size_t)s * KVDIM + h * HD;
        float gv = g[lane];
        v[lane] = v[lane] / (1.0f + __expf(-gv));
    }
}

// ---------------------------------------------------------------------------
// Flash attention v3: 2 q-rows/lane, NO running max (post-RMSNorm scores are
// bounded: |s| <= 8*8/sqrt(32) = 11.3 -> exp <= 8e4, l <= 1.7e8, safely fp32;
// softmax is shift-invariant so semantics are identical). Per key: 1 FMA/dim
// per row, K/V broadcast rows feed 128 FMAs. 4 waves split-K with wave-
// private LDS tiles; plain-sum merge. Work-balanced 1D grid: block i pairs
// with i+256 -> every CU gets exactly 72 key-tiles.
// ---------------------------------------------------------------------------
__global__ __launch_bounds__(256, 2) void attn_kernel(
    const float* __restrict__ Qp, const float* __restrict__ Kp,
    const float* __restrict__ Vp, float* __restrict__ Aout) {
    __shared__ float lds[9216];           // 4 waves * (K 32x36 + V 32x36)
    __shared__ float lbuf[3][64];
    const int id = blockIdx.x;
    int qt, h, half;
    if (id < 256) { qt = 15 - (id & 15); h = (id >> 4); half = 0; }
    else { const int j = id - 256; qt = j & 15; h = (j >> 4); half = 1; }
    const int kvh  = h >> 2;
    const int tid  = threadIdx.x;
    const int w    = tid >> 6;
    const int lane = tid & 63;
    const int r0   = qt * 128 + lane;
    const int r1   = r0 + 64;
    float* KsW = &lds[w * 2304];
    float* VsW = KsW + 1152;

    float q0[32], q1[32], acc0[32] = {}, acc1[32] = {};
    {
        const float* p0 = Qp + (size_t)r0 * DIM + h * HD + half * 32;
        const float* p1 = Qp + (size_t)r1 * DIM + h * HD + half * 32;
        #pragma unroll
        for (int d = 0; d < 32; d += 4) {
            *(float4*)&q0[d] = *(const float4*)(p0 + d);
            *(float4*)&q1[d] = *(const float4*)(p1 + d);
        }
    }
    float l0 = 0.f, l1 = 0.f;
    const float scale = 0.17677669529663687f;  // 1/sqrt(32)
    const int srow = lane >> 1;
    const int scol = (lane & 1) * 16;
    const int nkt = 4 * qt + 4;

    for (int kb = w; kb < nkt; kb += 4) {
        // wave-private staging (lockstep, no barrier)
        {
            const size_t base = (size_t)(kb * 32 + srow) * KVDIM + kvh * HD + half * 32 + scol;
            const float* kp = Kp + base;
            const float* vp = Vp + base;
            float* kd = &KsW[srow * 36 + scol];
            float* vd = &VsW[srow * 36 + scol];
            #pragma unroll
            for (int c = 0; c < 16; c += 4) {
                *(float4*)(kd + c) = *(const float4*)(kp + c);
                *(float4*)(vd + c) = *(const float4*)(vp + c);
            }
        }
        const int j0 = kb * 32;
        for (int j = 0; j < 32; ++j) {
            const float* kr = &KsW[j * 36];
            float s0 = 0.f, s1 = 0.f;
            #pragma unroll
            for (int d = 0; d < 32; d += 4) {
                float4 kv = *(const float4*)(kr + d);
                s0 += q0[d]*kv.x + q0[d+1]*kv.y + q0[d+2]*kv.z + q0[d+3]*kv.w;
                s1 += q1[d]*kv.x + q1[d+1]*kv.y + q1[d+2]*kv.z + q1[d+3]*kv.w;
            }
            const float p0 = (j0 + j > r0) ? 0.f : __expf(s0 * scale);
            const float p1 = (j0 + j > r1) ? 0.f : __expf(s1 * scale);
            l0 += p0; l1 += p1;
            const float* vr = &VsW[j * 36];
            #pragma unroll
            for (int d = 0; d < 32; d += 4) {
                float4 vv = *(const float4*)(vr + d);
                acc0[d]   += p0 * vv.x;  acc1[d]   += p1 * vv.x;
                acc0[d+1] += p0 * vv.y;  acc1[d+1] += p1 * vv.y;
                acc0[d+2] += p0 * vv.z;  acc1[d+2] += p1 * vv.z;
                acc0[d+3] += p0 * vv.w;  acc1[d+3] += p1 * vv.w;
            }
        }
    }

    // merge row0 (plain sums; stride-33 conflict-free)
    __syncthreads();
    if (w > 0) {
        float* dst = &lds[(w - 1) * 2112 + lane * 33];
        #pragma unroll
        for (int d = 0; d < 32; ++d) dst[d] = acc0[d];
        lbuf[w - 1][lane] = l0;
    }
    __syncthreads();
    if (w == 0) {
        #pragma unroll
        for (int p = 0; p < 3; ++p) {
            l0 += lbuf[p][lane];
            const float* src = &lds[p * 2112 + lane * 33];
            #pragma unroll
            for (int d = 0; d < 32; ++d) acc0[d] += src[d];
        }
    }
    __syncthreads();
    // merge row1
    if (w > 0) {
        float* dst = &lds[(w - 1) * 2112 + lane * 33];
        #pragma unroll
        for (int d = 0; d < 32; ++d) dst[d] = acc1[d];
        lbuf[w - 1][lane] = l1;
    }
    __syncthreads();
    if (w == 0) {
        #pragma unroll
        for (int p = 0; p < 3; ++p) {
            l1 += lbuf[p][lane];
            const float* src = &lds[p * 2112 + lane * 33];
            #pragma unroll
            for (int d = 0; d < 32; ++d) acc1[d] += src[d];
        }
        const float i0 = 1.f / l0, i1 = 1.f / l1;
        float* o0 = Aout + (size_t)r0 * DIM + h * HD + half * 32;
        float* o1 = Aout + (size_t)r1 * DIM + h * HD + half * 32;
        #pragma unroll
        for (int d = 0; d < 32; ++d) {
            o0[d] = acc0[d] * i0;
            o1[d] = acc1[d] * i1;
        }
    }
}

// ---------------------------------------------------------------------------
// Combine -> bf16 Y (feeds the MFMA output GEMM)
// ---------------------------------------------------------------------------
__global__ __launch_bounds__(256) void combine_kernel(
    const float* __restrict__ A, const float* __restrict__ lambda_p,
    bf16* __restrict__ Y) {
    const int idx = blockIdx.x * 256 + threadIdx.x;
    const int c = idx & (DIM - 1);
    const int s = idx >> 10;
    const int hh = c >> 6;
    const int d = c & 63;
    const float* base = A + (size_t)s * DIM + hh * HD;
    const float lam = lambda_p[hh];
    float y;
    if (d < 32) y = base[d]      - lam * base[d + 32];
    else        y = base[d - 32] + lam * base[d];
    Y[idx] = __float2bfloat16(y);
}

// ---------------------------------------------------------------------------
// Workspace (33 MB): Qp 0-8 | Kp 8-10 | Vp 10-12 | Gp 12-14 | Ao 14-22 |
// xb 22-26 | Wqb 26-28 | Wkb 28 | Wvb 29 | Wgb 30 | Wob 31-33 | Yb overlays Qp
// ---------------------------------------------------------------------------
extern "C" void kernel_launch(void* const* d_in, const int* in_sizes, int n_in,
                              void* d_out, int out_size, void* d_ws, size_t ws_size,
                              hipStream_t stream) {
    const float* x  = (const float*)d_in[0];
    const float* Wq = (const float*)d_in[1];
    const float* Wk = (const float*)d_in[2];
    const float* Wv = (const float*)d_in[3];
    const float* Wg = (const float*)d_in[4];
    const float* Wo = (const float*)d_in[5];
    const float* qg = (const float*)d_in[6];
    const float* lp = (const float*)d_in[7];
    float* out = (float*)d_out;

    char* ws = (char*)d_ws;
    float* Qp  = (float*)(ws);
    float* KVG = (float*)(ws + (8u  << 20));
    float* Kp  = KVG;
    float* Vp  = KVG + (size_t)S_LEN * KVDIM;
    float* Gp  = KVG + (size_t)2 * S_LEN * KVDIM;
    float* Ao  = (float*)(ws + (14u << 20));
    bf16* xb   = (bf16*)(ws + (22u << 20));
    bf16* Wqb  = (bf16*)(ws + (26u << 20));
    bf16* Wkb  = (bf16*)(ws + (28u << 20));
    bf16* Wvb  = (bf16*)(ws + (29u << 20));
    bf16* Wgb  = (bf16*)(ws + (30u << 20));
    bf16* Wob  = (bf16*)(ws + (31u << 20));
    bf16* Yb   = (bf16*)ws;               // overlays dead Qp

    // 0. Cast inputs to bf16
    cast_kernel<<<S_LEN*DIM/1024,   256, 0, stream>>>(x,  xb,  S_LEN*DIM);
    cast_kernel<<<DIM*DIM/1024,     256, 0, stream>>>(Wq, Wqb, DIM*DIM);
    cast_kernel<<<KVDIM*DIM/1024,   256, 0, stream>>>(Wk, Wkb, KVDIM*DIM);
    cast_kernel<<<KVDIM*DIM/1024,   256, 0, stream>>>(Wv, Wvb, KVDIM*DIM);
    cast_kernel<<<KVDIM*DIM/1024,   256, 0, stream>>>(Wg, Wgb, KVDIM*DIM);
    cast_kernel<<<DIM*DIM/1024,     256, 0, stream>>>(Wo, Wob, DIM*DIM);

    // 1. MFMA projections (fp32 accumulate/store)
    gemm_bf16<<<dim3(DIM/64, S_LEN/64), 256, 0, stream>>>(xb, Wqb, Qp, DIM, DIM);
    gemm_kvg_bf16<<<dim3(12, S_LEN/64), 256, 0, stream>>>(xb, Wkb, Wvb, Wgb, KVG);

    // 2. RMSNorm + rotary + gate (fp32, verified)
    postproc<<<dim3(S_LEN, NH + 2*NKVH), 64, 0, stream>>>(Qp, Kp, Vp, Gp, qg);

    // 3. Flash attention v3 (balanced 1D grid)
    attn_kernel<<<512, 256, 0, stream>>>(Qp, Kp, Vp, Ao);

    // 4. Lambda combine -> bf16 Y (overlays dead Qp)
    combine_kernel<<<S_LEN * DIM / 256, 256, 0, stream>>>(Ao, lp, Yb);

    // 5. MFMA output projection -> fp32 out
    gemm_bf16<<<dim3(DIM/64, S_LEN/64), 256, 0, stream>>>(Yb, Wob, out, DIM, DIM);
}

// Round 12
// 213.380 us; speedup vs baseline: 3.9860x; 1.7741x over previous
//
#include <hip/hip_runtime.h>
#include <hip/hip_bf16.h>
#include <math.h>

#define S_LEN 2048
#define DIM   1024
#define NH    16
#define NKVH  4
#define HD    64
#define KVDIM 256

typedef __hip_bfloat16 bf16;
typedef __attribute__((ext_vector_type(8))) short short8;   // 8 bf16 (4 VGPRs)
typedef __attribute__((ext_vector_type(4))) float f32x4;

// ---------------------------------------------------------------------------
// fp32 -> bf16 cast (n multiple of 4)
// ---------------------------------------------------------------------------
__global__ __launch_bounds__(256) void cast_kernel(
    const float* __restrict__ s, bf16* __restrict__ d, int n) {
    const int i = (blockIdx.x * 256 + threadIdx.x) * 4;
    if (i < n) {
        float4 v = *(const float4*)(s + i);
        d[i]     = __float2bfloat16(v.x);
        d[i + 1] = __float2bfloat16(v.y);
        d[i + 2] = __float2bfloat16(v.z);
        d[i + 3] = __float2bfloat16(v.w);
    }
}

// ---------------------------------------------------------------------------
// bf16 MFMA GEMM (verified round 11): C[M,N] = A[M,K]*B[N,K]^T, fp32 out.
// ---------------------------------------------------------------------------
__device__ __forceinline__ void gemm_core(
    const bf16* __restrict__ A, const bf16* __restrict__ B,
    float* __restrict__ C, int bm, int bn, int N, int K) {
    __shared__ short As[64 * 72];
    __shared__ short Bs[64 * 72];
    const int tid  = threadIdx.x;
    const int w    = tid >> 6;
    const int lane = tid & 63;
    const int quad = lane >> 4;
    const int lm   = lane & 15;
    const int row  = tid >> 2;
    const int kc   = (tid & 3) * 16;
    const bf16* ap = A + (size_t)(bm + row) * K + kc;
    const bf16* bp = B + (size_t)(bn + row) * K + kc;
    f32x4 acc[4] = {};
    const int aoff = (w * 16 + lm) * 72 + quad * 8;
    const int boff = lm * 72 + quad * 8;
    for (int k0 = 0; k0 < K; k0 += 64) {
        uint4 av0 = *(const uint4*)(ap + k0);
        uint4 av1 = *(const uint4*)(ap + k0 + 8);
        uint4 bv0 = *(const uint4*)(bp + k0);
        uint4 bv1 = *(const uint4*)(bp + k0 + 8);
        *(uint4*)&As[row * 72 + kc]     = av0;
        *(uint4*)&As[row * 72 + kc + 8] = av1;
        *(uint4*)&Bs[row * 72 + kc]     = bv0;
        *(uint4*)&Bs[row * 72 + kc + 8] = bv1;
        __syncthreads();
        short8 a0 = *(const short8*)&As[aoff];
        short8 a1 = *(const short8*)&As[aoff + 32];
        #pragma unroll
        for (int t = 0; t < 4; ++t) {
            short8 b0 = *(const short8*)&Bs[boff + t * 16 * 72];
            short8 b1 = *(const short8*)&Bs[boff + t * 16 * 72 + 32];
            acc[t] = __builtin_amdgcn_mfma_f32_16x16x32_bf16(a0, b0, acc[t], 0, 0, 0);
            acc[t] = __builtin_amdgcn_mfma_f32_16x16x32_bf16(a1, b1, acc[t], 0, 0, 0);
        }
        __syncthreads();
    }
    const int r0 = bm + w * 16 + quad * 4;
    #pragma unroll
    for (int t = 0; t < 4; ++t) {
        const int col = bn + t * 16 + lm;
        #pragma unroll
        for (int i = 0; i < 4; ++i)
            C[(size_t)(r0 + i) * N + col] = acc[t][i];
    }
}

__global__ __launch_bounds__(256) void gemm_bf16(
    const bf16* __restrict__ A, const bf16* __restrict__ B,
    float* __restrict__ C, int N, int K) {
    gemm_core(A, B, C, blockIdx.y * 64, blockIdx.x * 64, N, K);
}

__global__ __launch_bounds__(256) void gemm_kvg_bf16(
    const bf16* __restrict__ A, const bf16* __restrict__ Bk,
    const bf16* __restrict__ Bv, const bf16* __restrict__ Bg,
    float* __restrict__ KVG) {
    const int wsel = blockIdx.x >> 2;
    const bf16* B = (wsel == 0) ? Bk : (wsel == 1) ? Bv : Bg;
    float* C = KVG + (size_t)wsel * S_LEN * KVDIM;
    gemm_core(A, B, C, blockIdx.y * 64, (blockIdx.x & 3) * 64, KVDIM, DIM);
}

// ---------------------------------------------------------------------------
// Postproc: fp32 in -> bf16 out (Q,K rms+rotary; V sigmoid gate).
// Math identical to the verified fp32 version; only the store dtype changed.
// ---------------------------------------------------------------------------
__device__ __forceinline__ void rms_rotary_b(
    const float* __restrict__ p, bf16* __restrict__ pb, int s, int lane, float gain) {
    float x = p[lane];
    float ss = x * x;
    #pragma unroll
    for (int o = 32; o > 0; o >>= 1) ss += __shfl_xor(ss, o);
    float n = x * rsqrtf(ss * (1.0f/64.0f) + 1.1920928955078125e-7f);
    float other = __shfl_xor(n, 32);
    int i = lane & 31;
    float af  = (float)(((double)(2*i) / 64.0) * 3.14159265358979323846);
    float ang = (float)s * af;
    float radius = 1.0f / (1.0f + 0.01f * (float)s);
    float c  = radius * (float)cos((double)ang);
    float sn = radius * (float)sin((double)ang);
    float out = n * c + ((lane < 32) ? other * sn : -other * sn);
    pb[lane] = __float2bfloat16(out * gain);
}

__global__ __launch_bounds__(64) void postproc_b(
    const float* __restrict__ Qp, const float* __restrict__ Kp,
    const float* __restrict__ Vp, const float* __restrict__ Gp,
    bf16* __restrict__ Qb, bf16* __restrict__ Kb, bf16* __restrict__ Vb,
    const float* __restrict__ qgain) {
    const int s = blockIdx.x;
    const int unit = blockIdx.y;
    const int lane = threadIdx.x;
    if (unit < NH) {
        rms_rotary_b(Qp + (size_t)s * DIM + unit * HD,
                     Qb + (size_t)s * DIM + unit * HD, s, lane, qgain[unit]);
    } else if (unit < NH + NKVH) {
        rms_rotary_b(Kp + (size_t)s * KVDIM + (unit - NH) * HD,
                     Kb + (size_t)s * KVDIM + (unit - NH) * HD, s, lane, 1.0f);
    } else {
        const int h = unit - NH - NKVH;
        const float* v = Vp + (size_t)s * KVDIM + h * HD;
        const float* g = Gp + (size_t)s * KVDIM + h * HD;
        bf16* vb = Vb + (size_t)s * KVDIM + h * HD;
        float gv = g[lane];
        vb[lane] = __float2bfloat16(v[lane] / (1.0f + __expf(-gv)));
    }
}

// ---------------------------------------------------------------------------
// MFMA flash attention. Grid: 1024 blocks = (32 qtiles x 64 rows) x 32
// head-halves; id>>5 = reversed qtile (heavy first), id&31 = head-half.
// Block = 4 waves; wave w owns rows [qt*64+w*16, +16). Zero barriers:
//  - Q A-frag loaded once from global (A[m=lane&15][k=quad*8+j], verified).
//  - K B-frags loaded per tile straight from global (B[n=key][k=dim]).
//  - V^T staged per wave into private, double-buffered LDS (transposed for
//    the PV B-operand B[n=dim][k=key]).
//  - Scores exp'd in fp32 WITHOUT max-subtraction (bounded: |s|<=11.3 after
//    RMSNorm, verified R11) -> O accumulates directly in MFMA C-regs across
//    all key tiles, no rescaling. P round-trips C-layout -> A-layout via
//    wave-private LDS (m120-verified transform).
//  - l via per-lane partials + shfl_xor over the 16 col-lanes of each quad.
// ---------------------------------------------------------------------------
__global__ __launch_bounds__(256, 4) void attn_mfma(
    const bf16* __restrict__ Qb, const bf16* __restrict__ Kb,
    const bf16* __restrict__ Vb, float* __restrict__ Ao) {
    __shared__ short lds[4 * 2560 + 4 * 1280];  // 4x VT dbuf (2x32x40) + 4x P dbuf (2x16x40)
    const int id   = blockIdx.x;
    const int qt   = 31 - (id >> 5);
    const int hh   = id & 31;
    const int h    = hh >> 1;
    const int half = hh & 1;
    const int kvh  = h >> 2;
    const int tid  = threadIdx.x;
    const int w    = tid >> 6;
    const int lane = tid & 63;
    const int quad = lane >> 4;
    const int m    = lane & 15;
    short* VT0 = &lds[w * 2560];
    short* PW0 = &lds[4 * 2560 + w * 1280];

    // Q fragment (A-layout): row qt*64+w*16+m, dims quad*8..+8 of this half
    const int qrow = qt * 64 + w * 16 + m;
    short8 qf = *(const short8*)(Qb + (size_t)qrow * DIM + h * HD + half * 32 + quad * 8);

    f32x4 o0 = {}, o1 = {};
    float lpart[4] = {0.f, 0.f, 0.f, 0.f};
    const float scale = 0.17677669529663687f;   // 1/sqrt(32)
    const int rbase = qt * 64 + w * 16 + quad * 4;
    const int nkt = ((qt * 64 + w * 16 + 15) >> 5) + 1;  // per-wave early exit

    for (int kb = 0; kb < nkt; ++kb) {
        short* VT = VT0 + (kb & 1) * 1280;
        short* PW = PW0 + (kb & 1) * 640;
        // K B-frags straight from global: n = key, k = dim (quad*8..+8)
        const size_t kroff = kvh * HD + half * 32 + quad * 8;
        short8 kf0 = *(const short8*)(Kb + (size_t)(kb * 32 + m)      * KVDIM + kroff);
        short8 kf1 = *(const short8*)(Kb + (size_t)(kb * 32 + 16 + m) * KVDIM + kroff);
        f32x4 s0 = {}, s1 = {};
        s0 = __builtin_amdgcn_mfma_f32_16x16x32_bf16(qf, kf0, s0, 0, 0, 0);
        s1 = __builtin_amdgcn_mfma_f32_16x16x32_bf16(qf, kf1, s1, 0, 0, 0);
        // stage V^T (wave-private): lane reads key=lane>>1, 16 dims; writes transposed
        {
            const int vkey = lane >> 1, dh = lane & 1;
            const bf16* vp = Vb + (size_t)(kb * 32 + vkey) * KVDIM + kvh * HD + half * 32 + dh * 16;
            short8 v0 = *(const short8*)vp;
            short8 v1 = *(const short8*)(vp + 8);
            #pragma unroll
            for (int i = 0; i < 8; ++i) VT[(dh * 16 + i) * 40 + vkey]     = v0[i];
            #pragma unroll
            for (int i = 0; i < 8; ++i) VT[(dh * 16 + 8 + i) * 40 + vkey] = v1[i];
        }
        // exp + causal mask (fp32) -> P (bf16) in C-layout position
        const int kg = kb * 32 + m;
        bf16* PWb = (bf16*)PW;
        #pragma unroll
        for (int r = 0; r < 4; ++r) {
            const int rg = rbase + r;
            const float p0 = (kg > rg)      ? 0.f : __expf(s0[r] * scale);
            const float p1 = (kg + 16 > rg) ? 0.f : __expf(s1[r] * scale);
            lpart[r] += p0 + p1;
            PWb[(quad * 4 + r) * 40 + m]      = __float2bfloat16(p0);
            PWb[(quad * 4 + r) * 40 + 16 + m] = __float2bfloat16(p1);
        }
        // wave-level fence: all lanes' LDS writes drained before cross-lane reads
        asm volatile("s_waitcnt lgkmcnt(0)" ::: "memory");
        // P A-frag + V^T B-frags, accumulate O in MFMA C-regs
        short8 pf   = *(const short8*)&PW[m * 40 + quad * 8];
        short8 vtf0 = *(const short8*)&VT[m * 40 + quad * 8];
        short8 vtf1 = *(const short8*)&VT[(16 + m) * 40 + quad * 8];
        o0 = __builtin_amdgcn_mfma_f32_16x16x32_bf16(pf, vtf0, o0, 0, 0, 0);
        o1 = __builtin_amdgcn_mfma_f32_16x16x32_bf16(pf, vtf1, o1, 0, 0, 0);
    }

    // reduce l across the 16 col-lanes of each quad, then write O
    #pragma unroll
    for (int r = 0; r < 4; ++r) {
        float v = lpart[r];
        v += __shfl_xor(v, 1);
        v += __shfl_xor(v, 2);
        v += __shfl_xor(v, 4);
        v += __shfl_xor(v, 8);
        lpart[r] = 1.f / v;
    }
    #pragma unroll
    for (int r = 0; r < 4; ++r) {
        float* op = Ao + (size_t)(rbase + r) * DIM + h * HD + half * 32;
        op[m]      = o0[r] * lpart[r];
        op[16 + m] = o1[r] * lpart[r];
    }
}

// ---------------------------------------------------------------------------
// Combine -> bf16 Y (verified round 11)
// ---------------------------------------------------------------------------
__global__ __launch_bounds__(256) void combine_kernel(
    const float* __restrict__ A, const float* __restrict__ lambda_p,
    bf16* __restrict__ Y) {
    const int idx = blockIdx.x * 256 + threadIdx.x;
    const int c = idx & (DIM - 1);
    const int s = idx >> 10;
    const int hh = c >> 6;
    const int d = c & 63;
    const float* base = A + (size_t)s * DIM + hh * HD;
    const float lam = lambda_p[hh];
    float y;
    if (d < 32) y = base[d]      - lam * base[d + 32];
    else        y = base[d - 32] + lam * base[d];
    Y[idx] = __float2bfloat16(y);
}

// ---------------------------------------------------------------------------
// Workspace (33 MB):
//  0-8   Qp fp32 (dead after postproc) -> Yb bf16 overlays
//  8-14  KVG fp32 (dead after postproc)
//  14-22 Ao fp32
//  22-26 xb bf16 (dead after proj) -> Qb bf16 overlays
//  26-28 Wqb (dead after proj)     -> Kb 26-27, Vb 27-28 overlay
//  28-31 Wkb/Wvb/Wgb (dead after proj)
//  31-33 Wob (live till end)
// ---------------------------------------------------------------------------
extern "C" void kernel_launch(void* const* d_in, const int* in_sizes, int n_in,
                              void* d_out, int out_size, void* d_ws, size_t ws_size,
                              hipStream_t stream) {
    const float* x  = (const float*)d_in[0];
    const float* Wq = (const float*)d_in[1];
    const float* Wk = (const float*)d_in[2];
    const float* Wv = (const float*)d_in[3];
    const float* Wg = (const float*)d_in[4];
    const float* Wo = (const float*)d_in[5];
    const float* qg = (const float*)d_in[6];
    const float* lp = (const float*)d_in[7];
    float* out = (float*)d_out;

    char* ws = (char*)d_ws;
    float* Qp  = (float*)(ws);
    float* KVG = (float*)(ws + (8u  << 20));
    float* Kp  = KVG;
    float* Vp  = KVG + (size_t)S_LEN * KVDIM;
    float* Gp  = KVG + (size_t)2 * S_LEN * KVDIM;
    float* Ao  = (float*)(ws + (14u << 20));
    bf16* xb   = (bf16*)(ws + (22u << 20));
    bf16* Wqb  = (bf16*)(ws + (26u << 20));
    bf16* Wkb  = (bf16*)(ws + (28u << 20));
    bf16* Wvb  = (bf16*)(ws + (29u << 20));
    bf16* Wgb  = (bf16*)(ws + (30u << 20));
    bf16* Wob  = (bf16*)(ws + (31u << 20));
    bf16* Qb   = (bf16*)(ws + (22u << 20));  // overlays dead xb
    bf16* Kb   = (bf16*)(ws + (26u << 20));  // overlays dead Wqb
    bf16* Vb   = (bf16*)(ws + (27u << 20));
    bf16* Yb   = (bf16*)ws;                  // overlays dead Qp

    // 0. Cast inputs to bf16
    cast_kernel<<<S_LEN*DIM/1024, 256, 0, stream>>>(x,  xb,  S_LEN*DIM);
    cast_kernel<<<DIM*DIM/1024,   256, 0, stream>>>(Wq, Wqb, DIM*DIM);
    cast_kernel<<<KVDIM*DIM/1024, 256, 0, stream>>>(Wk, Wkb, KVDIM*DIM);
    cast_kernel<<<KVDIM*DIM/1024, 256, 0, stream>>>(Wv, Wvb, KVDIM*DIM);
    cast_kernel<<<KVDIM*DIM/1024, 256, 0, stream>>>(Wg, Wgb, KVDIM*DIM);
    cast_kernel<<<DIM*DIM/1024,   256, 0, stream>>>(Wo, Wob, DIM*DIM);

    // 1. MFMA projections (fp32 accumulate/store)
    gemm_bf16<<<dim3(DIM/64, S_LEN/64), 256, 0, stream>>>(xb, Wqb, Qp, DIM, DIM);
    gemm_kvg_bf16<<<dim3(12, S_LEN/64), 256, 0, stream>>>(xb, Wkb, Wvb, Wgb, KVG);

    // 2. RMSNorm + rotary + gate -> bf16 Q/K/V (Qb over xb, Kb/Vb over Wqb)
    postproc_b<<<dim3(S_LEN, NH + 2*NKVH), 64, 0, stream>>>(
        Qp, Kp, Vp, Gp, Qb, Kb, Vb, qg);

    // 3. MFMA flash attention
    attn_mfma<<<1024, 256, 0, stream>>>(Qb, Kb, Vb, Ao);

    // 4. Lambda combine -> bf16 Y (overlays dead Qp)
    combine_kernel<<<S_LEN * DIM / 256, 256, 0, stream>>>(Ao, lp, Yb);

    // 5. MFMA output projection -> fp32 out
    gemm_bf16<<<dim3(DIM/64, S_LEN/64), 256, 0, stream>>>(Yb, Wob, out, DIM, DIM);
}